// Round 14
// baseline (281.932 us; speedup 1.0000x reference)
//
#include <hip/hip_runtime.h>

constexpr int NB = 8, NA = 64, NT = 12, NH = 128, NTY = 8, NSC = 32, NAG = 16;

struct Params {
    const float *traj, *ntraj, *ty, *sd, *adata, *rel;
    const float *W_in, *b_in, *W_nt, *b_nt, *W_ag, *b_ag, *W_sc, *b_sc;
    const float *W_ein, *b_ein, *W_ety, *b_ety;
    const float *W_edge, *b_edge, *W_self, *b_self, *W_e2n, *b_e2n;
    const float *W_ih, *W_hh, *b_ih, *b_hh, *W_pred, *b_pred;
    float *h0, *h1, *c, *se, *R;
    float *Wty, *Wsc, *Wag, *Wcomb, *vbase, *vag, *vbe, *sesty, *Xs, *out;
};

// ---- Prelude: fold (blk 0-184) | r0+sesty+state-zero (blk 185-312, 4 rows/block) ----
__global__ __launch_bounds__(512) void k_prelude(Params p) {
    const int blk = blockIdx.x, tid = threadIdx.x;
    if (blk < 185) {
        const int c = tid;
        __shared__ float lrow[NH];
        __shared__ float b1[NH], b2[NH], b3[NH], b4[NH];
        if (blk < 184) {
            const float* src; int ihoff, row; float* dst;
            if (blk < 8)       { row = blk;      src = p.W_nt  + row * NH; ihoff = 128; dst = p.Wty; }
            else if (blk < 40) { row = blk - 8;  src = p.W_sc  + row * NH; ihoff = 384; dst = p.Wsc; }
            else if (blk < 56) { row = blk - 40; src = p.W_ag  + row * NH; ihoff = 512; dst = p.Wag; }
            else               { row = blk - 56; src = p.W_e2n + row * NH; ihoff = 256; dst = p.Wcomb; }
            if (c < NH) lrow[c] = src[c];
            __syncthreads();
            float acc = 0.f;
            for (int k = 0; k < NH; ++k) acc += lrow[k] * p.W_ih[(ihoff + k) * 512 + c];
            dst[row * 512 + c] = acc;
        } else {
            if (c < NH) { b1[c] = p.b_nt[c]; b2[c] = p.b_sc[c]; b3[c] = p.b_ag[c]; b4[c] = p.b_e2n[c]; }
            __syncthreads();
            float vb = p.b_ih[c] + p.b_hh[c], va = 0.f, ve = 0.f;
            for (int k = 0; k < NH; ++k) {
                vb += b1[k] * p.W_ih[(128 + k) * 512 + c] + b2[k] * p.W_ih[(384 + k) * 512 + c];
                va += b3[k] * p.W_ih[(512 + k) * 512 + c];
                ve += b4[k] * p.W_ih[(256 + k) * 512 + c];
            }
            p.vbase[c] = vb; p.vag[c] = va; p.vbe[c] = ve;
        }
    } else {
        const int r0g = (blk - 185) * 4;
        const int b = r0g >> 6;
        const int q = tid >> 7, n = tid & 127;
        const int row = r0g + q, i = row & 63;
        __shared__ float lf[NA][6];
        __shared__ float lt[NA][NTY];
        __shared__ float sumf[6], sumt[NTY];
        if (tid < NA) {
            int j = tid, rj = b * NA + j;
            for (int k = 0; k < 3; ++k) {
                lf[j][k]     = p.ntraj[(rj * NT + 0) * 3 + k];
                lf[j][3 + k] = p.traj [(rj * NT + 0) * 3 + k];
            }
            for (int k = 0; k < NTY; ++k) lt[j][k] = p.ty[rj * NTY + k];
        }
        p.h0[row * NH + n] = 0.f;
        __syncthreads();
        if (tid < 6) {
            float s = 0.f; for (int j = 0; j < NA; ++j) s += lf[j][tid];
            sumf[tid] = s;
        } else if (tid < 6 + NTY) {
            int k = tid - 6; float s = 0.f;
            for (int j = 0; j < NA; ++j) s += lt[j][k];
            sumt[k] = s;
        }
        __syncthreads();
        float acc_i = p.b_ein[n] + p.b_ety[n];
        for (int k = 0; k < 6; ++k)   acc_i += lf[i][k] * p.W_ein[k * NH + n];
        for (int k = 0; k < NTY; ++k) acc_i += lt[i][k] * (p.W_ein[(12 + k) * NH + n] + p.W_ety[k * NH + n]);
        float acc_j = 0.f;
        for (int k = 0; k < 6; ++k)   acc_j += sumf[k] * p.W_ein[(6 + k) * NH + n];
        for (int k = 0; k < NTY; ++k) acc_j += sumt[k] * (p.W_ein[(20 + k) * NH + n] + p.W_ety[(NTY + k) * NH + n]);
        p.R[row * NH + n] = 64.f * acc_i + acc_j;
        float sv = p.b_self[n];
        for (int k = 0; k < NTY; ++k) sv += lt[i][k] * p.W_self[(2 * NH + k) * NH + n];
        p.sesty[row * NH + n] = sv;
    }
}

// ---- X_static[(g,t), 512] for t=1..11 + fused step 0 ----
// Step 0 exact: gates0 = Xs[0]; c1 = sig(gi)*tanh(gg); h1 = sig(go)*tanh(c1);
// R1 = R0@W3 + 64*b_edge; se1 = sesty.
__global__ __launch_bounds__(512) void k_xstatic(Params p) {
    const int g = blockIdx.x, tid = threadIdx.x, b = g >> 6;
    __shared__ float coordL[NT][NH];
    __shared__ float sceneL[NT][NSC];
    __shared__ float agentL[NT][NAG];
    __shared__ float tyL[NTY];
    __shared__ float lg0[512];
    __shared__ float R0L[NH];
    __shared__ float psR[4][NH];
    const float relv = p.rel[g];
    for (int idx = tid; idx < NT * NH; idx += 512) {
        int r = idx >> 7, k = idx & 127;
        float acc = p.b_in[k];
        const float* nt = p.ntraj + (g * NT + r) * 3;
        const float* tr = p.traj  + (g * NT + r) * 3;
        for (int j = 0; j < 3; ++j) acc += nt[j] * p.W_in[j * NH + k] + tr[j] * p.W_in[(3 + j) * NH + k];
        coordL[r][k] = fmaxf(acc, 0.f);
    }
    for (int i = tid; i < NT * NSC; i += 512) { int r = i >> 5, k = i & 31; sceneL[r][k] = p.sd[(b * NT + r) * NSC + k]; }
    for (int i = tid; i < NT * NAG; i += 512) { int r = i >> 4, k = i & 15; agentL[r][k] = p.adata[(g * NT + r) * NAG + k] * relv; }
    if (tid < NTY) tyL[tid] = p.ty[g * NTY + tid];
    if (tid >= 512 - NH) R0L[tid - (512 - NH)] = p.R[g * NH + (tid - (512 - NH))];
    __syncthreads();
    const int c = tid;
    float base = p.vbase[c] + relv * p.vag[c];
    for (int i = 0; i < NTY; ++i) base += tyL[i] * p.Wty[i * 512 + c];
    const float vbeL = p.vbe[c];
    float acc[NT];
#pragma unroll
    for (int r = 0; r < NT; ++r) acc[r] = base + (r > 0 ? vbeL : 0.f);
    for (int k = 0; k < NH; ++k) { float w = p.W_ih[k * 512 + c];
#pragma unroll
        for (int r = 0; r < NT; ++r) acc[r] += coordL[r][k] * w; }
    for (int k = 0; k < NSC; ++k) { float w = p.Wsc[k * 512 + c];
#pragma unroll
        for (int r = 0; r < NT; ++r) acc[r] += sceneL[r][k] * w; }
    for (int k = 0; k < NAG; ++k) { float w = p.Wag[k * 512 + c];
#pragma unroll
        for (int r = 0; r < NT; ++r) acc[r] += agentL[r][k] * w; }
#pragma unroll
    for (int r = 1; r < NT; ++r) p.Xs[((size_t)(g * NT + r)) * 512 + c] = acc[r];
    // ---- fused step 0 ----
    lg0[c] = acc[0];
    // R1 partials: R0@W3, split-K 4x32.
    {
        const int kq = tid >> 7, n2 = tid & 127;
        float s = 0.f;
        const float* w3 = p.W_edge + 2 * NH * NH + n2;
#pragma unroll 8
        for (int k = 32 * kq; k < 32 * kq + 32; ++k) s += R0L[k] * w3[k * NH];
        psR[kq][n2] = s;
    }
    __syncthreads();
    if (tid < NH) {
        const int n = tid;
        float gi = lg0[n], gg = lg0[2 * NH + n], go = lg0[3 * NH + n];
        float si = 1.f / (1.f + expf(-gi));
        float so = 1.f / (1.f + expf(-go));
        float cn = si * tanhf(gg);                 // sig(gf)*c0 = 0 exactly
        float hn = so * tanhf(cn);
        p.c [g * NH + n] = cn;
        p.h1[g * NH + n] = hn;
        p.se[g * NH + n] = p.sesty[g * NH + n];
        p.R [g * NH + n] = psR[0][n] + psR[1][n] + psR[2][n] + psR[3][n] + 64.f * p.b_edge[n];
    }
}

// ---- One recurrence step (t = 1..11): 2 rows/block, 256 blocks x 1024 threads ----
// float4 weights; out[t-1] deferred-written; t==NT-1 epilogue writes out[11].
__global__ __launch_bounds__(1024) void k_step(Params p, int t) {
    const int tid = threadIdx.x;
    const int r0 = blockIdx.x * 2;
    const int b = r0 >> 6;
    const int n = tid & 127;
    const int g8 = tid >> 7;                 // 0..7
    const float* __restrict__ hcur = (t & 1) ? p.h1 : p.h0;
    float* hnxt = (t & 1) ? p.h0 : p.h1;

    __shared__ float lh[2][NH], lR[2][NH], lse[2][NH];
    __shared__ float psum[8][NH];                          // batch h-sum partials
    __shared__ float ps2[8][NH];                           // shw2 partials
    __shared__ __align__(16) float psA[4][8][2][NH];       // stage A partials [path][kq][row]
    __shared__ float psO[8][NH];                           // out-proj partials [kq*2+r]
    __shared__ float lagg[2][NH];
    __shared__ __align__(16) float lgp[8][2][512];         // gate partials [kq][row][col]

    // Phase 0: own-row state loads + batch h-sum partials.
    if (tid < 256) {
        int rr = tid >> 7, k = tid & 127;
        lh[rr][k]  = hcur[(r0 + rr) * NH + k];
        lR[rr][k]  = p.R [(r0 + rr) * NH + k];
        lse[rr][k] = p.se[(r0 + rr) * NH + k];
    }
    {
        float s = 0.f;
        const float* hb = hcur + (b * NA + g8 * 8) * NH + n;
#pragma unroll
        for (int j = 0; j < 8; ++j) s += hb[j * NH];
        psum[g8][n] = s;
    }
    __syncthreads();                          // B1

    // Phase 1: stage A (float4) + shw2 + out[t-1] partials.
    {
        const int pa  = tid >> 8;             // path
        const int kq  = (tid >> 5) & 7;       // K-eighth
        const int t32 = tid & 31;             // col-quad
        const float* wb = (pa == 0) ? p.W_edge
                        : (pa == 1) ? p.W_edge + 2 * NH * NH
                        : (pa == 2) ? p.W_self
                                    : p.W_self + NH * NH;
        const float* d0 = (pa == 1) ? lR[0] : (pa == 3) ? lse[0] : lh[0];
        const float* d1 = (pa == 1) ? lR[1] : (pa == 3) ? lse[1] : lh[1];
        const float4* wv = (const float4*)wb;
        float4 a0 = {0.f, 0.f, 0.f, 0.f}, a1 = {0.f, 0.f, 0.f, 0.f};
#pragma unroll
        for (int k = 16 * kq; k < 16 * kq + 16; ++k) {
            float4 w4 = wv[k * 32 + t32];
            float x0 = d0[k], x1 = d1[k];
            a0.x += x0 * w4.x; a0.y += x0 * w4.y; a0.z += x0 * w4.z; a0.w += x0 * w4.w;
            a1.x += x1 * w4.x; a1.y += x1 * w4.y; a1.z += x1 * w4.z; a1.w += x1 * w4.w;
        }
        *(float4*)&psA[pa][kq][0][4 * t32] = a0;
        *(float4*)&psA[pa][kq][1][4 * t32] = a1;
    }
    {
        float s = 0.f;
        const float* w2 = p.W_edge + NH * NH + n;
#pragma unroll
        for (int k = 16 * g8; k < 16 * g8 + 16; ++k) {
            float hv = psum[0][k] + psum[1][k] + psum[2][k] + psum[3][k]
                     + psum[4][k] + psum[5][k] + psum[6][k] + psum[7][k];
            s += hv * w2[k * NH];
        }
        ps2[g8][n] = s;
    }
    {
        const int r = g8 & 1, kq = g8 >> 1;
        float s = 0.f;
        const float* wp = p.W_pred + n;
#pragma unroll
        for (int k = 32 * kq; k < 32 * kq + 32; ++k) s += lh[r][k] * wp[k * NH];
        psO[g8][n] = s;
    }
    __syncthreads();                          // B2

    // Phase 2: combine shw2 + R_new/se_new/agg; write out[t-1] (threads 512-767).
    if (tid < 256) {
        int rr = tid >> 7, k = tid & 127;
        float shw2v = 0.f;
#pragma unroll
        for (int q = 0; q < 8; ++q) shw2v += ps2[q][k];
        float a1v = 0.f, a3v = 0.f, aSv = 0.f;
#pragma unroll
        for (int kq = 0; kq < 8; ++kq) {
            a1v += psA[0][kq][rr][k];
            a3v += psA[1][kq][rr][k];
            aSv += psA[2][kq][rr][k] + psA[3][kq][rr][k];
        }
        float Rn = 64.f * a1v + shw2v + a3v + 64.f * p.b_edge[k];
        float Sn = aSv + p.sesty[(r0 + rr) * NH + k];
        p.R [(r0 + rr) * NH + k] = Rn;
        p.se[(r0 + rr) * NH + k] = Sn;
        lagg[rr][k] = Rn + Sn;
    } else if (tid >= 512 && tid < 768) {
        const int rc = tid - 512, rr = rc >> 7, k = rc & 127;
        float v = psO[rr][k] + psO[2 + rr][k] + psO[4 + rr][k] + psO[6 + rr][k] + p.b_pred[k];
        p.out[((size_t)(r0 + rr) * NT + (t - 1)) * NH + k] = fmaxf(v, 0.f);
    }
    __syncthreads();                          // B3

    // Phase 3: gates (float4); 8 K-eighths x 128 col-quads, both rows per thread.
    {
        const int kq = tid >> 7;
        const int cq = tid & 127;
        float4 a0 = {0.f, 0.f, 0.f, 0.f}, a1 = {0.f, 0.f, 0.f, 0.f};
        if (kq == 0) {
            a0 = *(const float4*)&p.Xs[((size_t)r0 * NT + t) * 512 + 4 * cq];
            a1 = *(const float4*)&p.Xs[((size_t)(r0 + 1) * NT + t) * 512 + 4 * cq];
        }
        {
            const float4* wc = (const float4*)p.Wcomb;
            const float4* wh = (const float4*)p.W_hh;
#pragma unroll
            for (int k = 16 * kq; k < 16 * kq + 16; ++k) {
                float4 w4 = wc[k * 128 + cq];
                float g0 = lagg[0][k], g1 = lagg[1][k];
                a0.x += g0 * w4.x; a0.y += g0 * w4.y; a0.z += g0 * w4.z; a0.w += g0 * w4.w;
                a1.x += g1 * w4.x; a1.y += g1 * w4.y; a1.z += g1 * w4.z; a1.w += g1 * w4.w;
            }
#pragma unroll
            for (int k = 16 * kq; k < 16 * kq + 16; ++k) {
                float4 w4 = wh[k * 128 + cq];
                float h0v = lh[0][k], h1v = lh[1][k];
                a0.x += h0v * w4.x; a0.y += h0v * w4.y; a0.z += h0v * w4.z; a0.w += h0v * w4.w;
                a1.x += h1v * w4.x; a1.y += h1v * w4.y; a1.z += h1v * w4.z; a1.w += h1v * w4.w;
            }
        }
        *(float4*)&lgp[kq][0][4 * cq] = a0;
        *(float4*)&lgp[kq][1][4 * cq] = a1;
    }
    __syncthreads();                          // B4

    // Phase 4: combine 8 K-eighths + LSTM elementwise; publish h (also into lh).
    if (tid < 256) {
        const int rr = tid >> 7, k = tid & 127, g = r0 + rr;
        float gi = 0.f, gf = 0.f, gg = 0.f, go = 0.f;
#pragma unroll
        for (int kq = 0; kq < 8; ++kq) {
            gi += lgp[kq][rr][k];
            gf += lgp[kq][rr][NH + k];
            gg += lgp[kq][rr][2 * NH + k];
            go += lgp[kq][rr][3 * NH + k];
        }
        float si = 1.f / (1.f + expf(-gi));
        float sf = 1.f / (1.f + expf(-gf));
        float so = 1.f / (1.f + expf(-go));
        float cn = sf * p.c[g * NH + k] + si * tanhf(gg);
        float hn = so * tanhf(cn);
        p.c[g * NH + k] = cn;
        hnxt[g * NH + k] = hn;
        lh[rr][k] = hn;
    }

    // Last step: emit out[NT-1] from h_NT (in lh).
    if (t == NT - 1) {
        __syncthreads();                      // B5
        {
            const int r = g8 & 1, kq = g8 >> 1;
            float s = 0.f;
            const float* wp = p.W_pred + n;
#pragma unroll
            for (int k = 32 * kq; k < 32 * kq + 32; ++k) s += lh[r][k] * wp[k * NH];
            psO[g8][n] = s;
        }
        __syncthreads();                      // B6
        if (tid < 256) {
            const int rr = tid >> 7, k = tid & 127;
            float v = psO[rr][k] + psO[2 + rr][k] + psO[4 + rr][k] + psO[6 + rr][k] + p.b_pred[k];
            p.out[((size_t)(r0 + rr) * NT + (NT - 1)) * NH + k] = fmaxf(v, 0.f);
        }
    }
}

extern "C" void kernel_launch(void* const* d_in, const int* in_sizes, int n_in,
                              void* d_out, int out_size, void* d_ws, size_t ws_size,
                              hipStream_t stream) {
    const float* const* in = (const float* const*)d_in;
    Params p;
    p.traj = in[0]; p.ntraj = in[1]; p.ty = in[2]; p.sd = in[3]; p.adata = in[4]; p.rel = in[5];
    p.W_in = in[6]; p.b_in = in[7]; p.W_nt = in[8]; p.b_nt = in[9];
    p.W_ag = in[10]; p.b_ag = in[11]; p.W_sc = in[12]; p.b_sc = in[13];
    p.W_ein = in[14]; p.b_ein = in[15]; p.W_ety = in[16]; p.b_ety = in[17];
    p.W_edge = in[18]; p.b_edge = in[19]; p.W_self = in[20]; p.b_self = in[21];
    p.W_e2n = in[22]; p.b_e2n = in[23];
    p.W_ih = in[24]; p.W_hh = in[25]; p.b_ih = in[26]; p.b_hh = in[27];
    p.W_pred = in[28]; p.b_pred = in[29];

    float* ws = (float*)d_ws;
    const size_t S = (size_t)NB * NA * NH;   // 65536
    p.h0 = ws;                // zeroed by k_prelude
    p.h1 = ws + S;            // written by k_xstatic (step-0 fold)
    p.c  = ws + 2 * S;        // written by k_xstatic
    p.se = ws + 3 * S;        // written by k_xstatic
    p.R  = ws + 4 * S;        // R0 by k_prelude, R1 by k_xstatic
    float* w = ws + 5 * S;
    p.Wty   = w;              w += 8 * 512;
    p.Wsc   = w;              w += 32 * 512;
    p.Wag   = w;              w += 16 * 512;
    p.Wcomb = w;              w += 128 * 512;
    p.vbase = w;              w += 512;
    p.vag   = w;              w += 512;
    p.vbe   = w;              w += 512;
    p.sesty = w;              w += (size_t)NB * NA * NH;
    p.Xs    = w;              w += (size_t)NB * NA * NT * 512;
    p.out = (float*)d_out;

    k_prelude<<<313, 512, 0, stream>>>(p);                     // fold | r0 | zeros
    k_xstatic<<<NB * NA, 512, 0, stream>>>(p);                 // xstatic + step 0
    for (int t = 1; t < NT; ++t)
        k_step<<<NB * NA / 2, 1024, 0, stream>>>(p, t);        // steps 1..11 (+out[11] epilogue)
}

// Round 15
// 281.884 us; speedup vs baseline: 1.0002x; 1.0002x over previous
//
#include <hip/hip_runtime.h>

constexpr int NB = 8, NA = 64, NT = 12, NH = 128, NTY = 8, NSC = 32, NAG = 16;

struct Params {
    const float *traj, *ntraj, *ty, *sd, *adata, *rel;
    const float *W_in, *b_in, *W_nt, *b_nt, *W_ag, *b_ag, *W_sc, *b_sc;
    const float *W_ein, *b_ein, *W_ety, *b_ety;
    const float *W_edge, *b_edge, *W_self, *b_self, *W_e2n, *b_e2n;
    const float *W_ih, *W_hh, *b_ih, *b_hh, *W_pred, *b_pred;
    float *h0, *h1, *c, *se, *R;
    float *Wty, *Wsc, *Wag, *Wcomb, *vbase, *vag, *vbe, *sesty, *Xs, *out;
};

// ---- Prelude: fold (blk 0-184) | r0+sesty+state-zero (blk 185-312, 4 rows/block) ----
__global__ __launch_bounds__(512) void k_prelude(Params p) {
    const int blk = blockIdx.x, tid = threadIdx.x;
    if (blk < 185) {
        const int c = tid;
        __shared__ float lrow[NH];
        __shared__ float b1[NH], b2[NH], b3[NH], b4[NH];
        if (blk < 184) {
            const float* src; int ihoff, row; float* dst;
            if (blk < 8)       { row = blk;      src = p.W_nt  + row * NH; ihoff = 128; dst = p.Wty; }
            else if (blk < 40) { row = blk - 8;  src = p.W_sc  + row * NH; ihoff = 384; dst = p.Wsc; }
            else if (blk < 56) { row = blk - 40; src = p.W_ag  + row * NH; ihoff = 512; dst = p.Wag; }
            else               { row = blk - 56; src = p.W_e2n + row * NH; ihoff = 256; dst = p.Wcomb; }
            if (c < NH) lrow[c] = src[c];
            __syncthreads();
            float acc = 0.f;
            for (int k = 0; k < NH; ++k) acc += lrow[k] * p.W_ih[(ihoff + k) * 512 + c];
            dst[row * 512 + c] = acc;
        } else {
            if (c < NH) { b1[c] = p.b_nt[c]; b2[c] = p.b_sc[c]; b3[c] = p.b_ag[c]; b4[c] = p.b_e2n[c]; }
            __syncthreads();
            float vb = p.b_ih[c] + p.b_hh[c], va = 0.f, ve = 0.f;
            for (int k = 0; k < NH; ++k) {
                vb += b1[k] * p.W_ih[(128 + k) * 512 + c] + b2[k] * p.W_ih[(384 + k) * 512 + c];
                va += b3[k] * p.W_ih[(512 + k) * 512 + c];
                ve += b4[k] * p.W_ih[(256 + k) * 512 + c];
            }
            p.vbase[c] = vb; p.vag[c] = va; p.vbe[c] = ve;
        }
    } else {
        const int r0g = (blk - 185) * 4;
        const int b = r0g >> 6;
        const int q = tid >> 7, n = tid & 127;
        const int row = r0g + q, i = row & 63;
        __shared__ float lf[NA][6];
        __shared__ float lt[NA][NTY];
        __shared__ float sumf[6], sumt[NTY];
        if (tid < NA) {
            int j = tid, rj = b * NA + j;
            for (int k = 0; k < 3; ++k) {
                lf[j][k]     = p.ntraj[(rj * NT + 0) * 3 + k];
                lf[j][3 + k] = p.traj [(rj * NT + 0) * 3 + k];
            }
            for (int k = 0; k < NTY; ++k) lt[j][k] = p.ty[rj * NTY + k];
        }
        p.h0[row * NH + n] = 0.f;
        __syncthreads();
        if (tid < 6) {
            float s = 0.f; for (int j = 0; j < NA; ++j) s += lf[j][tid];
            sumf[tid] = s;
        } else if (tid < 6 + NTY) {
            int k = tid - 6; float s = 0.f;
            for (int j = 0; j < NA; ++j) s += lt[j][k];
            sumt[k] = s;
        }
        __syncthreads();
        float acc_i = p.b_ein[n] + p.b_ety[n];
        for (int k = 0; k < 6; ++k)   acc_i += lf[i][k] * p.W_ein[k * NH + n];
        for (int k = 0; k < NTY; ++k) acc_i += lt[i][k] * (p.W_ein[(12 + k) * NH + n] + p.W_ety[k * NH + n]);
        float acc_j = 0.f;
        for (int k = 0; k < 6; ++k)   acc_j += sumf[k] * p.W_ein[(6 + k) * NH + n];
        for (int k = 0; k < NTY; ++k) acc_j += sumt[k] * (p.W_ein[(20 + k) * NH + n] + p.W_ety[(NTY + k) * NH + n]);
        p.R[row * NH + n] = 64.f * acc_i + acc_j;
        float sv = p.b_self[n];
        for (int k = 0; k < NTY; ++k) sv += lt[i][k] * p.W_self[(2 * NH + k) * NH + n];
        p.sesty[row * NH + n] = sv;
    }
}

// ---- X_static[(g,t), 512] for t=1..11 + fused step 0 ----
// Step 0 exact: gates0 = Xs[0]; c1 = sig(gi)*tanh(gg); h1 = sig(go)*tanh(c1);
// R1 = R0@W3 + 64*b_edge; se1 = sesty.
__global__ __launch_bounds__(512) void k_xstatic(Params p) {
    const int g = blockIdx.x, tid = threadIdx.x, b = g >> 6;
    __shared__ float coordL[NT][NH];
    __shared__ float sceneL[NT][NSC];
    __shared__ float agentL[NT][NAG];
    __shared__ float tyL[NTY];
    __shared__ float lg0[512];
    __shared__ float R0L[NH];
    __shared__ float psR[4][NH];
    const float relv = p.rel[g];
    for (int idx = tid; idx < NT * NH; idx += 512) {
        int r = idx >> 7, k = idx & 127;
        float acc = p.b_in[k];
        const float* nt = p.ntraj + (g * NT + r) * 3;
        const float* tr = p.traj  + (g * NT + r) * 3;
        for (int j = 0; j < 3; ++j) acc += nt[j] * p.W_in[j * NH + k] + tr[j] * p.W_in[(3 + j) * NH + k];
        coordL[r][k] = fmaxf(acc, 0.f);
    }
    for (int i = tid; i < NT * NSC; i += 512) { int r = i >> 5, k = i & 31; sceneL[r][k] = p.sd[(b * NT + r) * NSC + k]; }
    for (int i = tid; i < NT * NAG; i += 512) { int r = i >> 4, k = i & 15; agentL[r][k] = p.adata[(g * NT + r) * NAG + k] * relv; }
    if (tid < NTY) tyL[tid] = p.ty[g * NTY + tid];
    if (tid >= 512 - NH) R0L[tid - (512 - NH)] = p.R[g * NH + (tid - (512 - NH))];
    __syncthreads();
    const int c = tid;
    float base = p.vbase[c] + relv * p.vag[c];
    for (int i = 0; i < NTY; ++i) base += tyL[i] * p.Wty[i * 512 + c];
    const float vbeL = p.vbe[c];
    float acc[NT];
#pragma unroll
    for (int r = 0; r < NT; ++r) acc[r] = base + (r > 0 ? vbeL : 0.f);
    for (int k = 0; k < NH; ++k) { float w = p.W_ih[k * 512 + c];
#pragma unroll
        for (int r = 0; r < NT; ++r) acc[r] += coordL[r][k] * w; }
    for (int k = 0; k < NSC; ++k) { float w = p.Wsc[k * 512 + c];
#pragma unroll
        for (int r = 0; r < NT; ++r) acc[r] += sceneL[r][k] * w; }
    for (int k = 0; k < NAG; ++k) { float w = p.Wag[k * 512 + c];
#pragma unroll
        for (int r = 0; r < NT; ++r) acc[r] += agentL[r][k] * w; }
#pragma unroll
    for (int r = 1; r < NT; ++r) p.Xs[((size_t)(g * NT + r)) * 512 + c] = acc[r];
    // ---- fused step 0 ----
    lg0[c] = acc[0];
    {
        const int kq = tid >> 7, n2 = tid & 127;
        float s = 0.f;
        const float* w3 = p.W_edge + 2 * NH * NH + n2;
#pragma unroll 8
        for (int k = 32 * kq; k < 32 * kq + 32; ++k) s += R0L[k] * w3[k * NH];
        psR[kq][n2] = s;
    }
    __syncthreads();
    if (tid < NH) {
        const int n = tid;
        float gi = lg0[n], gg = lg0[2 * NH + n], go = lg0[3 * NH + n];
        float si = 1.f / (1.f + expf(-gi));
        float so = 1.f / (1.f + expf(-go));
        float cn = si * tanhf(gg);                 // sig(gf)*c0 = 0 exactly
        float hn = so * tanhf(cn);
        p.c [g * NH + n] = cn;
        p.h1[g * NH + n] = hn;
        p.se[g * NH + n] = p.sesty[g * NH + n];
        p.R [g * NH + n] = psR[0][n] + psR[1][n] + psR[2][n] + psR[3][n] + 64.f * p.b_edge[n];
    }
}

// ---- One recurrence step (t = 1..11): 2 rows/block, 256 blocks x 1024 threads ----
// __launch_bounds__(1024, 4): 4 waves/EU = 16 waves/CU => VGPR cap 128.
// Round 14's epilogue pushed VGPR>128 and halved occupancy (+8.4us/step);
// the bound forces the allocator to keep the hot phases at 16 waves/CU and
// spill (cheaply) only in the cold last-step epilogue.
__global__ __launch_bounds__(1024, 4) void k_step(Params p, int t) {
    const int tid = threadIdx.x;
    const int r0 = blockIdx.x * 2;
    const int b = r0 >> 6;
    const int n = tid & 127;
    const int g8 = tid >> 7;                 // 0..7
    const float* __restrict__ hcur = (t & 1) ? p.h1 : p.h0;
    float* hnxt = (t & 1) ? p.h0 : p.h1;

    __shared__ float lh[2][NH], lR[2][NH], lse[2][NH];
    __shared__ float psum[8][NH];                          // batch h-sum partials
    __shared__ float ps2[8][NH];                           // shw2 partials
    __shared__ __align__(16) float psA[4][8][2][NH];       // stage A partials [path][kq][row]
    __shared__ float psO[8][NH];                           // out-proj partials [kq*2+r]
    __shared__ float lagg[2][NH];
    __shared__ __align__(16) float lgp[8][2][512];         // gate partials [kq][row][col]

    // Phase 0: own-row state loads + batch h-sum partials.
    if (tid < 256) {
        int rr = tid >> 7, k = tid & 127;
        lh[rr][k]  = hcur[(r0 + rr) * NH + k];
        lR[rr][k]  = p.R [(r0 + rr) * NH + k];
        lse[rr][k] = p.se[(r0 + rr) * NH + k];
    }
    {
        float s = 0.f;
        const float* hb = hcur + (b * NA + g8 * 8) * NH + n;
#pragma unroll
        for (int j = 0; j < 8; ++j) s += hb[j * NH];
        psum[g8][n] = s;
    }
    __syncthreads();                          // B1

    // Phase 1: stage A (float4) + shw2 + out[t-1] partials.
    {
        const int pa  = tid >> 8;             // path
        const int kq  = (tid >> 5) & 7;       // K-eighth
        const int t32 = tid & 31;             // col-quad
        const float* wb = (pa == 0) ? p.W_edge
                        : (pa == 1) ? p.W_edge + 2 * NH * NH
                        : (pa == 2) ? p.W_self
                                    : p.W_self + NH * NH;
        const float* d0 = (pa == 1) ? lR[0] : (pa == 3) ? lse[0] : lh[0];
        const float* d1 = (pa == 1) ? lR[1] : (pa == 3) ? lse[1] : lh[1];
        const float4* wv = (const float4*)wb;
        float4 a0 = {0.f, 0.f, 0.f, 0.f}, a1 = {0.f, 0.f, 0.f, 0.f};
#pragma unroll
        for (int k = 16 * kq; k < 16 * kq + 16; ++k) {
            float4 w4 = wv[k * 32 + t32];
            float x0 = d0[k], x1 = d1[k];
            a0.x += x0 * w4.x; a0.y += x0 * w4.y; a0.z += x0 * w4.z; a0.w += x0 * w4.w;
            a1.x += x1 * w4.x; a1.y += x1 * w4.y; a1.z += x1 * w4.z; a1.w += x1 * w4.w;
        }
        *(float4*)&psA[pa][kq][0][4 * t32] = a0;
        *(float4*)&psA[pa][kq][1][4 * t32] = a1;
    }
    {
        float s = 0.f;
        const float* w2 = p.W_edge + NH * NH + n;
#pragma unroll
        for (int k = 16 * g8; k < 16 * g8 + 16; ++k) {
            float hv = psum[0][k] + psum[1][k] + psum[2][k] + psum[3][k]
                     + psum[4][k] + psum[5][k] + psum[6][k] + psum[7][k];
            s += hv * w2[k * NH];
        }
        ps2[g8][n] = s;
    }
    {
        const int r = g8 & 1, kq = g8 >> 1;
        float s = 0.f;
        const float* wp = p.W_pred + n;
#pragma unroll
        for (int k = 32 * kq; k < 32 * kq + 32; ++k) s += lh[r][k] * wp[k * NH];
        psO[g8][n] = s;
    }
    __syncthreads();                          // B2

    // Phase 2: combine shw2 + R_new/se_new/agg; write out[t-1] (threads 512-767).
    if (tid < 256) {
        int rr = tid >> 7, k = tid & 127;
        float shw2v = 0.f;
#pragma unroll
        for (int q = 0; q < 8; ++q) shw2v += ps2[q][k];
        float a1v = 0.f, a3v = 0.f, aSv = 0.f;
#pragma unroll
        for (int kq = 0; kq < 8; ++kq) {
            a1v += psA[0][kq][rr][k];
            a3v += psA[1][kq][rr][k];
            aSv += psA[2][kq][rr][k] + psA[3][kq][rr][k];
        }
        float Rn = 64.f * a1v + shw2v + a3v + 64.f * p.b_edge[k];
        float Sn = aSv + p.sesty[(r0 + rr) * NH + k];
        p.R [(r0 + rr) * NH + k] = Rn;
        p.se[(r0 + rr) * NH + k] = Sn;
        lagg[rr][k] = Rn + Sn;
    } else if (tid >= 512 && tid < 768) {
        const int rc = tid - 512, rr = rc >> 7, k = rc & 127;
        float v = psO[rr][k] + psO[2 + rr][k] + psO[4 + rr][k] + psO[6 + rr][k] + p.b_pred[k];
        p.out[((size_t)(r0 + rr) * NT + (t - 1)) * NH + k] = fmaxf(v, 0.f);
    }
    __syncthreads();                          // B3

    // Phase 3: gates (float4); 8 K-eighths x 128 col-quads, both rows per thread.
    {
        const int kq = tid >> 7;
        const int cq = tid & 127;
        float4 a0 = {0.f, 0.f, 0.f, 0.f}, a1 = {0.f, 0.f, 0.f, 0.f};
        if (kq == 0) {
            a0 = *(const float4*)&p.Xs[((size_t)r0 * NT + t) * 512 + 4 * cq];
            a1 = *(const float4*)&p.Xs[((size_t)(r0 + 1) * NT + t) * 512 + 4 * cq];
        }
        {
            const float4* wc = (const float4*)p.Wcomb;
            const float4* wh = (const float4*)p.W_hh;
#pragma unroll
            for (int k = 16 * kq; k < 16 * kq + 16; ++k) {
                float4 w4 = wc[k * 128 + cq];
                float g0 = lagg[0][k], g1 = lagg[1][k];
                a0.x += g0 * w4.x; a0.y += g0 * w4.y; a0.z += g0 * w4.z; a0.w += g0 * w4.w;
                a1.x += g1 * w4.x; a1.y += g1 * w4.y; a1.z += g1 * w4.z; a1.w += g1 * w4.w;
            }
#pragma unroll
            for (int k = 16 * kq; k < 16 * kq + 16; ++k) {
                float4 w4 = wh[k * 128 + cq];
                float h0v = lh[0][k], h1v = lh[1][k];
                a0.x += h0v * w4.x; a0.y += h0v * w4.y; a0.z += h0v * w4.z; a0.w += h0v * w4.w;
                a1.x += h1v * w4.x; a1.y += h1v * w4.y; a1.z += h1v * w4.z; a1.w += h1v * w4.w;
            }
        }
        *(float4*)&lgp[kq][0][4 * cq] = a0;
        *(float4*)&lgp[kq][1][4 * cq] = a1;
    }
    __syncthreads();                          // B4

    // Phase 4: combine 8 K-eighths + LSTM elementwise; publish h (also into lh).
    if (tid < 256) {
        const int rr = tid >> 7, k = tid & 127, g = r0 + rr;
        float gi = 0.f, gf = 0.f, gg = 0.f, go = 0.f;
#pragma unroll
        for (int kq = 0; kq < 8; ++kq) {
            gi += lgp[kq][rr][k];
            gf += lgp[kq][rr][NH + k];
            gg += lgp[kq][rr][2 * NH + k];
            go += lgp[kq][rr][3 * NH + k];
        }
        float si = 1.f / (1.f + expf(-gi));
        float sf = 1.f / (1.f + expf(-gf));
        float so = 1.f / (1.f + expf(-go));
        float cn = sf * p.c[g * NH + k] + si * tanhf(gg);
        float hn = so * tanhf(cn);
        p.c[g * NH + k] = cn;
        hnxt[g * NH + k] = hn;
        lh[rr][k] = hn;
    }

    // Last step: emit out[NT-1] from h_NT (in lh).
    if (t == NT - 1) {
        __syncthreads();                      // B5
        {
            const int r = g8 & 1, kq = g8 >> 1;
            float s = 0.f;
            const float* wp = p.W_pred + n;
#pragma unroll
            for (int k = 32 * kq; k < 32 * kq + 32; ++k) s += lh[r][k] * wp[k * NH];
            psO[g8][n] = s;
        }
        __syncthreads();                      // B6
        if (tid < 256) {
            const int rr = tid >> 7, k = tid & 127;
            float v = psO[rr][k] + psO[2 + rr][k] + psO[4 + rr][k] + psO[6 + rr][k] + p.b_pred[k];
            p.out[((size_t)(r0 + rr) * NT + (NT - 1)) * NH + k] = fmaxf(v, 0.f);
        }
    }
}

extern "C" void kernel_launch(void* const* d_in, const int* in_sizes, int n_in,
                              void* d_out, int out_size, void* d_ws, size_t ws_size,
                              hipStream_t stream) {
    const float* const* in = (const float* const*)d_in;
    Params p;
    p.traj = in[0]; p.ntraj = in[1]; p.ty = in[2]; p.sd = in[3]; p.adata = in[4]; p.rel = in[5];
    p.W_in = in[6]; p.b_in = in[7]; p.W_nt = in[8]; p.b_nt = in[9];
    p.W_ag = in[10]; p.b_ag = in[11]; p.W_sc = in[12]; p.b_sc = in[13];
    p.W_ein = in[14]; p.b_ein = in[15]; p.W_ety = in[16]; p.b_ety = in[17];
    p.W_edge = in[18]; p.b_edge = in[19]; p.W_self = in[20]; p.b_self = in[21];
    p.W_e2n = in[22]; p.b_e2n = in[23];
    p.W_ih = in[24]; p.W_hh = in[25]; p.b_ih = in[26]; p.b_hh = in[27];
    p.W_pred = in[28]; p.b_pred = in[29];

    float* ws = (float*)d_ws;
    const size_t S = (size_t)NB * NA * NH;   // 65536
    p.h0 = ws;                // zeroed by k_prelude
    p.h1 = ws + S;            // written by k_xstatic (step-0 fold)
    p.c  = ws + 2 * S;        // written by k_xstatic
    p.se = ws + 3 * S;        // written by k_xstatic
    p.R  = ws + 4 * S;        // R0 by k_prelude, R1 by k_xstatic
    float* w = ws + 5 * S;
    p.Wty   = w;              w += 8 * 512;
    p.Wsc   = w;              w += 32 * 512;
    p.Wag   = w;              w += 16 * 512;
    p.Wcomb = w;              w += 128 * 512;
    p.vbase = w;              w += 512;
    p.vag   = w;              w += 512;
    p.vbe   = w;              w += 512;
    p.sesty = w;              w += (size_t)NB * NA * NH;
    p.Xs    = w;              w += (size_t)NB * NA * NT * 512;
    p.out = (float*)d_out;

    k_prelude<<<313, 512, 0, stream>>>(p);                     // fold | r0 | zeros
    k_xstatic<<<NB * NA, 512, 0, stream>>>(p);                 // xstatic + step 0
    for (int t = 1; t < NT; ++t)
        k_step<<<NB * NA / 2, 1024, 0, stream>>>(p, t);        // steps 1..11 (+out[11] epilogue)
}

// Round 16
// 190.076 us; speedup vs baseline: 1.4833x; 1.4830x over previous
//
#include <hip/hip_runtime.h>

constexpr int NB = 8, NA = 64, NT = 12, NH = 128, NTY = 8, NSC = 32, NAG = 16;

struct Params {
    const float *traj, *ntraj, *ty, *sd, *adata, *rel;
    const float *W_in, *b_in, *W_nt, *b_nt, *W_ag, *b_ag, *W_sc, *b_sc;
    const float *W_ein, *b_ein, *W_ety, *b_ety;
    const float *W_edge, *b_edge, *W_self, *b_self, *W_e2n, *b_e2n;
    const float *W_ih, *W_hh, *b_ih, *b_hh, *W_pred, *b_pred;
    float *h0, *h1, *c, *se, *R;
    float *Wty, *Wsc, *Wag, *Wcomb, *vbase, *vag, *vbe, *sesty, *Xs, *out;
};

// ---- Prelude: fold (blk 0-184) | r0+sesty+state-zero (blk 185-312, 4 rows/block) ----
__global__ __launch_bounds__(512) void k_prelude(Params p) {
    const int blk = blockIdx.x, tid = threadIdx.x;
    if (blk < 185) {
        const int c = tid;
        __shared__ float lrow[NH];
        __shared__ float b1[NH], b2[NH], b3[NH], b4[NH];
        if (blk < 184) {
            const float* src; int ihoff, row; float* dst;
            if (blk < 8)       { row = blk;      src = p.W_nt  + row * NH; ihoff = 128; dst = p.Wty; }
            else if (blk < 40) { row = blk - 8;  src = p.W_sc  + row * NH; ihoff = 384; dst = p.Wsc; }
            else if (blk < 56) { row = blk - 40; src = p.W_ag  + row * NH; ihoff = 512; dst = p.Wag; }
            else               { row = blk - 56; src = p.W_e2n + row * NH; ihoff = 256; dst = p.Wcomb; }
            if (c < NH) lrow[c] = src[c];
            __syncthreads();
            float acc = 0.f;
            for (int k = 0; k < NH; ++k) acc += lrow[k] * p.W_ih[(ihoff + k) * 512 + c];
            dst[row * 512 + c] = acc;
        } else {
            if (c < NH) { b1[c] = p.b_nt[c]; b2[c] = p.b_sc[c]; b3[c] = p.b_ag[c]; b4[c] = p.b_e2n[c]; }
            __syncthreads();
            float vb = p.b_ih[c] + p.b_hh[c], va = 0.f, ve = 0.f;
            for (int k = 0; k < NH; ++k) {
                vb += b1[k] * p.W_ih[(128 + k) * 512 + c] + b2[k] * p.W_ih[(384 + k) * 512 + c];
                va += b3[k] * p.W_ih[(512 + k) * 512 + c];
                ve += b4[k] * p.W_ih[(256 + k) * 512 + c];
            }
            p.vbase[c] = vb; p.vag[c] = va; p.vbe[c] = ve;
        }
    } else {
        const int r0g = (blk - 185) * 4;
        const int b = r0g >> 6;
        const int q = tid >> 7, n = tid & 127;
        const int row = r0g + q, i = row & 63;
        __shared__ float lf[NA][6];
        __shared__ float lt[NA][NTY];
        __shared__ float sumf[6], sumt[NTY];
        if (tid < NA) {
            int j = tid, rj = b * NA + j;
            for (int k = 0; k < 3; ++k) {
                lf[j][k]     = p.ntraj[(rj * NT + 0) * 3 + k];
                lf[j][3 + k] = p.traj [(rj * NT + 0) * 3 + k];
            }
            for (int k = 0; k < NTY; ++k) lt[j][k] = p.ty[rj * NTY + k];
        }
        p.h0[row * NH + n] = 0.f;
        p.c [row * NH + n] = 0.f;
        p.se[row * NH + n] = 0.f;
        __syncthreads();
        if (tid < 6) {
            float s = 0.f; for (int j = 0; j < NA; ++j) s += lf[j][tid];
            sumf[tid] = s;
        } else if (tid < 6 + NTY) {
            int k = tid - 6; float s = 0.f;
            for (int j = 0; j < NA; ++j) s += lt[j][k];
            sumt[k] = s;
        }
        __syncthreads();
        float acc_i = p.b_ein[n] + p.b_ety[n];
        for (int k = 0; k < 6; ++k)   acc_i += lf[i][k] * p.W_ein[k * NH + n];
        for (int k = 0; k < NTY; ++k) acc_i += lt[i][k] * (p.W_ein[(12 + k) * NH + n] + p.W_ety[k * NH + n]);
        float acc_j = 0.f;
        for (int k = 0; k < 6; ++k)   acc_j += sumf[k] * p.W_ein[(6 + k) * NH + n];
        for (int k = 0; k < NTY; ++k) acc_j += sumt[k] * (p.W_ein[(20 + k) * NH + n] + p.W_ety[(NTY + k) * NH + n]);
        p.R[row * NH + n] = 64.f * acc_i + acc_j;
        float sv = p.b_self[n];
        for (int k = 0; k < NTY; ++k) sv += lt[i][k] * p.W_self[(2 * NH + k) * NH + n];
        p.sesty[row * NH + n] = sv;
    }
}

// ---- X_static[(g,t), 512]; vbe folded in for t>0 ----
__global__ __launch_bounds__(512) void k_xstatic(Params p) {
    const int g = blockIdx.x, tid = threadIdx.x, b = g >> 6;
    __shared__ float coordL[NT][NH];
    __shared__ float sceneL[NT][NSC];
    __shared__ float agentL[NT][NAG];
    __shared__ float tyL[NTY];
    const float relv = p.rel[g];
    for (int idx = tid; idx < NT * NH; idx += 512) {
        int r = idx >> 7, k = idx & 127;
        float acc = p.b_in[k];
        const float* nt = p.ntraj + (g * NT + r) * 3;
        const float* tr = p.traj  + (g * NT + r) * 3;
        for (int j = 0; j < 3; ++j) acc += nt[j] * p.W_in[j * NH + k] + tr[j] * p.W_in[(3 + j) * NH + k];
        coordL[r][k] = fmaxf(acc, 0.f);
    }
    for (int i = tid; i < NT * NSC; i += 512) { int r = i >> 5, k = i & 31; sceneL[r][k] = p.sd[(b * NT + r) * NSC + k]; }
    for (int i = tid; i < NT * NAG; i += 512) { int r = i >> 4, k = i & 15; agentL[r][k] = p.adata[(g * NT + r) * NAG + k] * relv; }
    if (tid < NTY) tyL[tid] = p.ty[g * NTY + tid];
    __syncthreads();
    const int c = tid;
    float base = p.vbase[c] + relv * p.vag[c];
    for (int i = 0; i < NTY; ++i) base += tyL[i] * p.Wty[i * 512 + c];
    const float vbeL = p.vbe[c];
    float acc[NT];
#pragma unroll
    for (int r = 0; r < NT; ++r) acc[r] = base + (r > 0 ? vbeL : 0.f);
    for (int k = 0; k < NH; ++k) { float w = p.W_ih[k * 512 + c];
#pragma unroll
        for (int r = 0; r < NT; ++r) acc[r] += coordL[r][k] * w; }
    for (int k = 0; k < NSC; ++k) { float w = p.Wsc[k * 512 + c];
#pragma unroll
        for (int r = 0; r < NT; ++r) acc[r] += sceneL[r][k] * w; }
    for (int k = 0; k < NAG; ++k) { float w = p.Wag[k * 512 + c];
#pragma unroll
        for (int r = 0; r < NT; ++r) acc[r] += agentL[r][k] * w; }
#pragma unroll
    for (int r = 0; r < NT; ++r) p.Xs[((size_t)(g * NT + r)) * 512 + c] = acc[r];
}

// ---- One recurrence step: 2 rows/block, 256 blocks x 1024 threads, fp32 ----
// Round-12 structure; stage A and gates use float4 weight loads. t == NT: tail
// emits out[NT-1].
__global__ __launch_bounds__(1024) void k_step(Params p, int t) {
    const int tid = threadIdx.x;
    const int r0 = blockIdx.x * 2;
    const int b = r0 >> 6;
    const int n = tid & 127;
    const int g8 = tid >> 7;                 // 0..7
    const float* __restrict__ hcur = (t & 1) ? p.h1 : p.h0;
    float* hnxt = (t & 1) ? p.h0 : p.h1;

    __shared__ float lh[2][NH], lR[2][NH], lse[2][NH];
    __shared__ float psum[8][NH];                          // batch h-sum partials
    __shared__ float ps2[8][NH];                           // shw2 partials
    __shared__ __align__(16) float psA[4][8][2][NH];       // stage A partials [path][kq][row]
    __shared__ float psO[8][NH];                           // out-proj partials [kq*2+r]
    __shared__ float lagg[2][NH];
    __shared__ __align__(16) float lgp[8][2][512];         // gate partials [kq][row][col]

    // ---- Tail: out[NT-1] from hcur ----
    if (t == NT) {
        if (tid < 256) lh[tid >> 7][tid & 127] = hcur[(r0 + (tid >> 7)) * NH + (tid & 127)];
        __syncthreads();
        {
            const int r = g8 & 1, kq = g8 >> 1;
            float s = 0.f;
            const float* wp = p.W_pred + n;
#pragma unroll
            for (int k = 32 * kq; k < 32 * kq + 32; ++k) s += lh[r][k] * wp[k * NH];
            psO[g8][n] = s;
        }
        __syncthreads();
        if (tid < 256) {
            const int rr = tid >> 7, k = tid & 127;
            float v = psO[rr][k] + psO[2 + rr][k] + psO[4 + rr][k] + psO[6 + rr][k] + p.b_pred[k];
            p.out[((size_t)(r0 + rr) * NT + (NT - 1)) * NH + k] = fmaxf(v, 0.f);
        }
        return;
    }

    // Phase 0: own-row state loads + batch h-sum partials.
    if (tid < 256) {
        int rr = tid >> 7, k = tid & 127;
        lh[rr][k]  = hcur[(r0 + rr) * NH + k];
        lR[rr][k]  = p.R [(r0 + rr) * NH + k];
        lse[rr][k] = p.se[(r0 + rr) * NH + k];
    }
    if (t > 0) {
        float s = 0.f;
        const float* hb = hcur + (b * NA + g8 * 8) * NH + n;
#pragma unroll
        for (int j = 0; j < 8; ++j) s += hb[j * NH];
        psum[g8][n] = s;
    }
    __syncthreads();                          // B1

    // Phase 1: stage A (float4) + shw2 + out[t-1] partials.
    {
        const int pa  = tid >> 8;             // 0..3 path
        const int kq  = (tid >> 5) & 7;       // K-eighth
        const int t32 = tid & 31;             // col-quad
        const float* wb = (pa == 0) ? p.W_edge
                        : (pa == 1) ? p.W_edge + 2 * NH * NH
                        : (pa == 2) ? p.W_self
                                    : p.W_self + NH * NH;
        const float* d0 = (pa == 1) ? lR[0] : (pa == 3) ? lse[0] : lh[0];
        const float* d1 = (pa == 1) ? lR[1] : (pa == 3) ? lse[1] : lh[1];
        const float4* wv = (const float4*)wb;
        float4 a0 = {0.f, 0.f, 0.f, 0.f}, a1 = {0.f, 0.f, 0.f, 0.f};
#pragma unroll
        for (int k = 16 * kq; k < 16 * kq + 16; ++k) {
            float4 w4 = wv[k * 32 + t32];
            float x0 = d0[k], x1 = d1[k];
            a0.x += x0 * w4.x; a0.y += x0 * w4.y; a0.z += x0 * w4.z; a0.w += x0 * w4.w;
            a1.x += x1 * w4.x; a1.y += x1 * w4.y; a1.z += x1 * w4.z; a1.w += x1 * w4.w;
        }
        *(float4*)&psA[pa][kq][0][4 * t32] = a0;
        *(float4*)&psA[pa][kq][1][4 * t32] = a1;
    }
    if (t > 0) {
        float s = 0.f;
        const float* w2 = p.W_edge + NH * NH + n;
#pragma unroll
        for (int k = 16 * g8; k < 16 * g8 + 16; ++k) {
            float hv = psum[0][k] + psum[1][k] + psum[2][k] + psum[3][k]
                     + psum[4][k] + psum[5][k] + psum[6][k] + psum[7][k];
            s += hv * w2[k * NH];
        }
        ps2[g8][n] = s;
    }
    if (t > 0) {
        const int r = g8 & 1, kq = g8 >> 1;
        float s = 0.f;
        const float* wp = p.W_pred + n;
#pragma unroll
        for (int k = 32 * kq; k < 32 * kq + 32; ++k) s += lh[r][k] * wp[k * NH];
        psO[g8][n] = s;
    }
    __syncthreads();                          // B2

    // Phase 2: combine shw2 + R_new/se_new/agg; write out[t-1] (threads 512-767).
    if (tid < 256) {
        int rr = tid >> 7, k = tid & 127;
        float shw2v = 0.f;
        if (t > 0) {
#pragma unroll
            for (int q = 0; q < 8; ++q) shw2v += ps2[q][k];
        }
        float a1v = 0.f, a3v = 0.f, aSv = 0.f;
#pragma unroll
        for (int kq = 0; kq < 8; ++kq) {
            a1v += psA[0][kq][rr][k];
            a3v += psA[1][kq][rr][k];
            aSv += psA[2][kq][rr][k] + psA[3][kq][rr][k];
        }
        float Rn = 64.f * a1v + shw2v + a3v + 64.f * p.b_edge[k];
        float Sn = aSv + p.sesty[(r0 + rr) * NH + k];
        p.R [(r0 + rr) * NH + k] = Rn;
        p.se[(r0 + rr) * NH + k] = Sn;
        lagg[rr][k] = Rn + Sn;
    } else if (tid >= 512 && tid < 768 && t > 0) {
        const int rc = tid - 512, rr = rc >> 7, k = rc & 127;
        float v = psO[rr][k] + psO[2 + rr][k] + psO[4 + rr][k] + psO[6 + rr][k] + p.b_pred[k];
        p.out[((size_t)(r0 + rr) * NT + (t - 1)) * NH + k] = fmaxf(v, 0.f);
    }
    __syncthreads();                          // B3

    // Phase 3: gates (float4); 8 K-eighths x 128 col-quads, both rows per thread.
    {
        const int kq = tid >> 7;              // K-eighth
        const int cq = tid & 127;             // col-quad (cols 4cq..4cq+3)
        float4 a0 = {0.f, 0.f, 0.f, 0.f}, a1 = {0.f, 0.f, 0.f, 0.f};
        if (kq == 0) {
            a0 = *(const float4*)&p.Xs[((size_t)r0 * NT + t) * 512 + 4 * cq];
            a1 = *(const float4*)&p.Xs[((size_t)(r0 + 1) * NT + t) * 512 + 4 * cq];
        }
        if (t > 0) {
            const float4* wc = (const float4*)p.Wcomb;
            const float4* wh = (const float4*)p.W_hh;
#pragma unroll
            for (int k = 16 * kq; k < 16 * kq + 16; ++k) {
                float4 w4 = wc[k * 128 + cq];
                float g0 = lagg[0][k], g1 = lagg[1][k];
                a0.x += g0 * w4.x; a0.y += g0 * w4.y; a0.z += g0 * w4.z; a0.w += g0 * w4.w;
                a1.x += g1 * w4.x; a1.y += g1 * w4.y; a1.z += g1 * w4.z; a1.w += g1 * w4.w;
            }
#pragma unroll
            for (int k = 16 * kq; k < 16 * kq + 16; ++k) {
                float4 w4 = wh[k * 128 + cq];
                float h0v = lh[0][k], h1v = lh[1][k];
                a0.x += h0v * w4.x; a0.y += h0v * w4.y; a0.z += h0v * w4.z; a0.w += h0v * w4.w;
                a1.x += h1v * w4.x; a1.y += h1v * w4.y; a1.z += h1v * w4.z; a1.w += h1v * w4.w;
            }
        }
        *(float4*)&lgp[kq][0][4 * cq] = a0;
        *(float4*)&lgp[kq][1][4 * cq] = a1;
    }
    __syncthreads();                          // B4

    // Phase 4: combine 8 K-eighths + LSTM elementwise; publish h.
    if (tid < 256) {
        const int rr = tid >> 7, k = tid & 127, g = r0 + rr;
        float gi = 0.f, gf = 0.f, gg = 0.f, go = 0.f;
#pragma unroll
        for (int kq = 0; kq < 8; ++kq) {
            gi += lgp[kq][rr][k];
            gf += lgp[kq][rr][NH + k];
            gg += lgp[kq][rr][2 * NH + k];
            go += lgp[kq][rr][3 * NH + k];
        }
        float si = 1.f / (1.f + expf(-gi));
        float sf = 1.f / (1.f + expf(-gf));
        float so = 1.f / (1.f + expf(-go));
        float cn = sf * p.c[g * NH + k] + si * tanhf(gg);
        float hn = so * tanhf(cn);
        p.c[g * NH + k] = cn;
        hnxt[g * NH + k] = hn;
    }
}

extern "C" void kernel_launch(void* const* d_in, const int* in_sizes, int n_in,
                              void* d_out, int out_size, void* d_ws, size_t ws_size,
                              hipStream_t stream) {
    const float* const* in = (const float* const*)d_in;
    Params p;
    p.traj = in[0]; p.ntraj = in[1]; p.ty = in[2]; p.sd = in[3]; p.adata = in[4]; p.rel = in[5];
    p.W_in = in[6]; p.b_in = in[7]; p.W_nt = in[8]; p.b_nt = in[9];
    p.W_ag = in[10]; p.b_ag = in[11]; p.W_sc = in[12]; p.b_sc = in[13];
    p.W_ein = in[14]; p.b_ein = in[15]; p.W_ety = in[16]; p.b_ety = in[17];
    p.W_edge = in[18]; p.b_edge = in[19]; p.W_self = in[20]; p.b_self = in[21];
    p.W_e2n = in[22]; p.b_e2n = in[23];
    p.W_ih = in[24]; p.W_hh = in[25]; p.b_ih = in[26]; p.b_hh = in[27];
    p.W_pred = in[28]; p.b_pred = in[29];

    float* ws = (float*)d_ws;
    const size_t S = (size_t)NB * NA * NH;   // 65536
    p.h0 = ws;                // zeroed by k_prelude
    p.h1 = ws + S;            // written at t=0 before any read
    p.c  = ws + 2 * S;        // zeroed by k_prelude
    p.se = ws + 3 * S;        // zeroed by k_prelude
    p.R  = ws + 4 * S;        // k_prelude
    float* w = ws + 5 * S;
    p.Wty   = w;              w += 8 * 512;
    p.Wsc   = w;              w += 32 * 512;
    p.Wag   = w;              w += 16 * 512;
    p.Wcomb = w;              w += 128 * 512;
    p.vbase = w;              w += 512;
    p.vag   = w;              w += 512;
    p.vbe   = w;              w += 512;
    p.sesty = w;              w += (size_t)NB * NA * NH;
    p.Xs    = w;              w += (size_t)NB * NA * NT * 512;
    p.out = (float*)d_out;

    k_prelude<<<313, 512, 0, stream>>>(p);                     // fold | r0 | zeros
    k_xstatic<<<NB * NA, 512, 0, stream>>>(p);
    for (int t = 0; t < NT; ++t)
        k_step<<<NB * NA / 2, 1024, 0, stream>>>(p, t);
    k_step<<<NB * NA / 2, 1024, 0, stream>>>(p, NT);           // tail: out[11]
}